// Round 9
// baseline (436.515 us; speedup 1.0000x reference)
//
#include <hip/hip_runtime.h>
#include <stdint.h>
#include <stddef.h>

typedef __attribute__((ext_vector_type(4))) float f32x4;
typedef __attribute__((ext_vector_type(4))) int   i32x4;

constexpr int B = 4, P = 48000, C = 64, NY = 496, NX = 432, CMAP = 16;
constexpr int CT  = C + CMAP;            // 80 output channels
constexpr int X4  = NX / 4;              // 108 float4 groups per full row
constexpr int CQ  = C / 4;               // 16 channel quads
constexpr size_t PL = (size_t)NY * NX;   // 214,272 channel-plane stride

// map transpose tile geometry (exact: 432 = 48*9, 496 = 16*31)
constexpr int XT   = 48;
constexpr int YT   = 16;
constexpr int NRUN = CMAP * YT;          // 256 output runs per tile
constexpr int LSTR = XT + 4;             // 52 words: aligned b128, bank-spread
constexpr int NYT  = NY / YT;            // 31 y-tiles

// Amplification factor for self-measuring dispatches (idempotent passes).
constexpr int AMP = 3;

// Pass A: build inverse map cell -> point id (cells unique by construction)
__global__ void scatter_inv_kernel(const int* __restrict__ coords,
                                   int* __restrict__ inv) {
    int p = blockIdx.x * blockDim.x + threadIdx.x;
    if (p >= P) return;
    const int4 cd = ((const int4*)coords)[p];     // (b, 0, y, x)
    inv[(cd.x * NY + cd.z) * NX + cd.w] = p;
}

// Pass B: vox dense fill, AMP self-measuring passes. Pass p handles
// cq = (cq0 + 5p) & 15 — bijective per pass, so EVERY pass is a complete
// correct fill (cross-pass duplicate writes carry identical values).
// Rotation makes addresses AND gathered data pass-dependent: no sinking.
__global__ void __launch_bounds__(256) vox_fill_kernel(
        const float* __restrict__ vox, const int* __restrict__ inv,
        float* __restrict__ out) {
    const int x4  = threadIdx.x & 127;
    if (x4 >= X4) return;                          // 20 idle lanes / 128
    const int y   = (blockIdx.y << 1) | (threadIdx.x >> 7);
    const int bcq = blockIdx.z;                    // b*16 + cq0
    const int cq0 = bcq & (CQ - 1);
    const int b   = bcq >> 4;

    const i32x4 p4 = ((const i32x4*)inv)[(b * NY + y) * X4 + x4];
    const f32x4* vox4 = (const f32x4*)vox;         // vox row = 16 f32x4
    const bool any = (p4.x & p4.y & p4.z & p4.w) >= 0;

    #pragma unroll 1
    for (int pass = 0; pass < AMP; ++pass) {
        const int cq = (cq0 + pass * 5) & (CQ - 1);

        f32x4 r0 = (f32x4)0.f, r1 = (f32x4)0.f, r2 = (f32x4)0.f, r3 = (f32x4)0.f;
        if (any) {
            if (p4.x >= 0) r0 = vox4[(size_t)p4.x * CQ + cq];
            if (p4.y >= 0) r1 = vox4[(size_t)p4.y * CQ + cq];
            if (p4.z >= 0) r2 = vox4[(size_t)p4.z * CQ + cq];
            if (p4.w >= 0) r3 = vox4[(size_t)p4.w * CQ + cq];
        }

        float* ob = out + (((size_t)b * CT + cq * 4) * NY + y) * NX + x4 * 4;
        f32x4 s;
        s.x = r0.x; s.y = r1.x; s.z = r2.x; s.w = r3.x;
        __builtin_nontemporal_store(s, (f32x4*)(ob));
        s.x = r0.y; s.y = r1.y; s.z = r2.y; s.w = r3.y;
        __builtin_nontemporal_store(s, (f32x4*)(ob + PL));
        s.x = r0.z; s.y = r1.z; s.z = r2.z; s.w = r3.z;
        __builtin_nontemporal_store(s, (f32x4*)(ob + 2 * PL));
        s.x = r0.w; s.y = r1.w; s.z = r2.w; s.w = r3.w;
        __builtin_nontemporal_store(s, (f32x4*)(ob + 3 * PL));
    }
}

// Pass C: map transpose (r8 coalesced-read structure), AMP self-measuring
// passes over rotated y-tiles ((t + 7p) mod 31 — bijective per pass).
__global__ void __launch_bounds__(256) map_xpose_kernel(
        const float* __restrict__ map, float* __restrict__ out) {
    __shared__ __align__(16) float m_s[NRUN * LSTR];   // 52 KB

    const int tid = threadIdx.x;
    const int x0  = blockIdx.x * XT;
    const int b   = blockIdx.z;
    const f32x4* map4 = (const f32x4*)map;

    #pragma unroll 1
    for (int pass = 0; pass < AMP; ++pass) {
        int t = blockIdx.y + pass * 7;
        t -= (t >= NYT) ? NYT : 0;
        t -= (t >= NYT) ? NYT : 0;                 // t mod 31 (max 30+14)
        const int y0 = t * YT;

        // read: 48 runs of 1KB contiguous (one full wave-load per x).
        #pragma unroll
        for (int k = 0; k < 12; ++k) {
            int idx = k * 256 + tid;
            int xi  = idx >> 6;
            int qi  = idx & 63;
            f32x4 mv = map4[(size_t)(b * NX + x0 + xi) * (NY * CMAP / 4)
                            + (size_t)y0 * (CMAP / 4) + qi];
            int yl  = qi >> 2;
            int cm0 = (qi & 3) * 4;
            m_s[((cm0 + 0) * YT + yl) * LSTR + xi] = mv.x;
            m_s[((cm0 + 1) * YT + yl) * LSTR + xi] = mv.y;
            m_s[((cm0 + 2) * YT + yl) * LSTR + xi] = mv.z;
            m_s[((cm0 + 3) * YT + yl) * LSTR + xi] = mv.w;
        }
        __syncthreads();

        // write: 256 runs (cm,y) x 12 quads of x; 192B line-aligned bursts.
        const size_t ob = ((size_t)b * CT + C) * PL + (size_t)y0 * NX + x0;
        #pragma unroll
        for (int k = 0; k < 12; ++k) {
            int idx = k * 256 + tid;
            int xq  = idx % 12;
            int run = idx / 12;
            int cm  = run >> 4, yl = run & 15;
            f32x4 v = *(const f32x4*)&m_s[run * LSTR + xq * 4];
            __builtin_nontemporal_store(v,
                (f32x4*)(out + ob + (size_t)cm * PL + (size_t)yl * NX + xq * 4));
        }
        __syncthreads();   // LDS reused next pass
    }
}

// ---------------- fallbacks ----------------
__global__ void zero_vox_region_kernel(float* __restrict__ out) {
    int g = blockIdx.x * 256 + threadIdx.x;
    if (g >= B * C * NY * X4) return;
    int x4   = g % X4;
    int rest = g / X4;
    int y  = rest % NY;
    int bc = rest / NY;
    int c  = bc & (C - 1);
    int b  = bc >> 6;
    *(f32x4*)(out + (((size_t)b * CT + c) * NY + y) * NX + x4 * 4) = (f32x4)0.f;
}

__global__ void scatter_direct_kernel(const float* __restrict__ vox,
                                      const int* __restrict__ coords,
                                      float* __restrict__ out) {
    int p = blockIdx.x;
    int c = threadIdx.x;  // 0..63
    const int4 cd = ((const int4*)coords)[p];
    out[(((size_t)cd.x * CT + c) * NY + cd.z) * NX + cd.w] = vox[(size_t)p * C + c];
}

__global__ void map_only_kernel(const float* __restrict__ map,
                                float* __restrict__ out) {
    int g = blockIdx.x * 256 + threadIdx.x;
    if (g >= B * CMAP * NY * NX) return;
    int x    = g % NX;
    int rest = g / NX;
    int y  = rest % NY;
    int bc = rest / NY;
    int cm = bc & (CMAP - 1);
    int b  = bc >> 4;
    out[((size_t)b * CT + C + cm) * PL + (size_t)y * NX + x] =
        map[((size_t)(b * NX + x) * NY + y) * CMAP + cm];
}

extern "C" void kernel_launch(void* const* d_in, const int* in_sizes, int n_in,
                              void* d_out, int out_size, void* d_ws, size_t ws_size,
                              hipStream_t stream) {
    const float* vox    = (const float*)d_in[0];   // (P, 64) float32
    const int*   coords = (const int*)d_in[1];     // (P, 4) int32
    const float* map    = (const float*)d_in[3];   // (B, NX, NY, CMAP) float32
    float* out = (float*)d_out;                    // (B, 80, NY, NX) float32

    const size_t inv_bytes = (size_t)B * NY * NX * sizeof(int);  // 3.43 MB
    int* inv = (ws_size >= inv_bytes) ? (int*)d_ws : nullptr;

    if (inv) {
        (void)hipMemsetAsync(inv, 0xFF, inv_bytes, stream);      // all -1
        scatter_inv_kernel<<<(P + 255) / 256, 256, 0, stream>>>(coords, inv);
        vox_fill_kernel<<<dim3(1, NY / 2, B * CQ), 256, 0, stream>>>(vox, inv, out);
        map_xpose_kernel<<<dim3(NX / XT, NYT, B), 256, 0, stream>>>(map, out);
    } else {
        zero_vox_region_kernel<<<(B * C * NY * X4 + 255) / 256, 256, 0, stream>>>(out);
        scatter_direct_kernel<<<P, 64, 0, stream>>>(vox, coords, out);
        map_only_kernel<<<(B * CMAP * NY * NX + 255) / 256, 256, 0, stream>>>(map, out);
    }
}

// Round 10
// 331.108 us; speedup vs baseline: 1.3183x; 1.3183x over previous
//
#include <hip/hip_runtime.h>
#include <stdint.h>
#include <stddef.h>

typedef __attribute__((ext_vector_type(4))) float f32x4;
typedef __attribute__((ext_vector_type(4))) int   i32x4;

constexpr int B = 4, P = 48000, C = 64, NY = 496, NX = 432, CMAP = 16;
constexpr int CT  = C + CMAP;            // 80 output channels
constexpr int X4  = NX / 4;              // 108 float4 groups per full row
constexpr int CQ  = C / 4;               // 16 channel quads
constexpr size_t PL = (size_t)NY * NX;   // 214,272 channel-plane stride

// map transpose tile geometry (exact: 432 = 48*9, 496 = 16*31)
constexpr int XT   = 48;                 // x per tile
constexpr int YT   = 16;                 // y per tile
constexpr int NRUN = CMAP * YT;          // 256 output runs per tile
constexpr int LSTR = XT + 4;             // 52 words: aligned b128, bank-spread
constexpr int NYT  = NY / YT;            // 31 y-tiles

// Pass A: build inverse map cell -> point id (cells unique by construction)
__global__ void scatter_inv_kernel(const int* __restrict__ coords,
                                   int* __restrict__ inv) {
    int p = blockIdx.x * blockDim.x + threadIdx.x;
    if (p >= P) return;
    const int4 cd = ((const int4*)coords)[p];     // (b, 0, y, x)
    inv[(cd.x * NY + cd.z) * NX + cd.w] = p;
}

// Pass B: vox dense fill. Geometry in the 3-D grid (zero div/mod); one
// thread = one (b,cq,y,x4) group: 1 int4 inv load, <=4 f32x4 gathers,
// 4 plane-strided NT stores. Measured (r9 amplification): runs at ~6.4 TB/s
// marginal — HBM roofline for its 219 MB writes + 12 MB gathers.
__global__ void __launch_bounds__(256) vox_fill_kernel(
        const float* __restrict__ vox, const int* __restrict__ inv,
        float* __restrict__ out) {
    const int x4  = threadIdx.x & 127;
    if (x4 >= X4) return;                          // 20 idle lanes / 128
    const int y   = (blockIdx.y << 1) | (threadIdx.x >> 7);
    const int bcq = blockIdx.z;                    // b*16 + cq
    const int cq  = bcq & (CQ - 1);
    const int b   = bcq >> 4;
    const int c0  = cq * 4;

    i32x4 p4 = ((const i32x4*)inv)[(b * NY + y) * X4 + x4];

    f32x4 r0 = (f32x4)0.f, r1 = (f32x4)0.f, r2 = (f32x4)0.f, r3 = (f32x4)0.f;
    // pids -1 (empty) or >=0; AND keeps sign bit only if ALL empty (~79%)
    if ((p4.x & p4.y & p4.z & p4.w) >= 0) {
        const f32x4* vox4 = (const f32x4*)vox;     // vox row = 16 f32x4
        if (p4.x >= 0) r0 = vox4[(size_t)p4.x * CQ + cq];
        if (p4.y >= 0) r1 = vox4[(size_t)p4.y * CQ + cq];
        if (p4.z >= 0) r2 = vox4[(size_t)p4.z * CQ + cq];
        if (p4.w >= 0) r3 = vox4[(size_t)p4.w * CQ + cq];
    }

    float* ob = out + (((size_t)b * CT + c0) * NY + y) * NX + x4 * 4;
    f32x4 s;
    s.x = r0.x; s.y = r1.x; s.z = r2.x; s.w = r3.x;
    __builtin_nontemporal_store(s, (f32x4*)(ob));
    s.x = r0.y; s.y = r1.y; s.z = r2.y; s.w = r3.y;
    __builtin_nontemporal_store(s, (f32x4*)(ob + PL));
    s.x = r0.z; s.y = r1.z; s.z = r2.z; s.w = r3.z;
    __builtin_nontemporal_store(s, (f32x4*)(ob + 2 * PL));
    s.x = r0.w; s.y = r1.w; s.z = r2.w; s.w = r3.w;
    __builtin_nontemporal_store(s, (f32x4*)(ob + 3 * PL));
}

// Pass C: map transpose with fully-coalesced reads. map is (B, NX, NY, CMAP):
// contiguous along (y, cm). Per tile (48x, 16y): read = 48 runs of 1KB
// contiguous (one full wave-load each); LDS transpose (stride 52 words);
// write = 256 runs of 192B line-aligned per (cm,y). Roofline per r9.
__global__ void __launch_bounds__(256) map_xpose_kernel(
        const float* __restrict__ map, float* __restrict__ out) {
    __shared__ __align__(16) float m_s[NRUN * LSTR];   // 52 KB

    const int tid = threadIdx.x;
    const int x0  = blockIdx.x * XT;              // 0..8 -> 0..384
    const int y0  = blockIdx.y * YT;              // 0..30 -> 0..480
    const int b   = blockIdx.z;

    const f32x4* map4 = (const f32x4*)map;
    // read: idx = xi*64 + qi; wave lanes sweep qi -> 1KB contiguous per x.
    #pragma unroll
    for (int k = 0; k < 12; ++k) {
        int idx = k * 256 + tid;
        int xi  = idx >> 6;                       // 0..47
        int qi  = idx & 63;                       // 0..63: (y,cm) quad
        f32x4 mv = map4[(size_t)(b * NX + x0 + xi) * (NY * CMAP / 4)
                        + (size_t)y0 * (CMAP / 4) + qi];
        int yl  = qi >> 2;                        // 0..15
        int cm0 = (qi & 3) * 4;
        m_s[((cm0 + 0) * YT + yl) * LSTR + xi] = mv.x;
        m_s[((cm0 + 1) * YT + yl) * LSTR + xi] = mv.y;
        m_s[((cm0 + 2) * YT + yl) * LSTR + xi] = mv.z;
        m_s[((cm0 + 3) * YT + yl) * LSTR + xi] = mv.w;
    }
    __syncthreads();

    // write: 256 runs (cm,y) x 12 quads of x; 192B line-aligned bursts.
    const size_t ob = ((size_t)b * CT + C) * PL + (size_t)y0 * NX + x0;
    #pragma unroll
    for (int k = 0; k < 12; ++k) {
        int idx = k * 256 + tid;
        int xq  = idx % 12;
        int run = idx / 12;                       // 0..255
        int cm  = run >> 4, yl = run & 15;
        f32x4 v = *(const f32x4*)&m_s[run * LSTR + xq * 4];
        __builtin_nontemporal_store(v,
            (f32x4*)(out + ob + (size_t)cm * PL + (size_t)yl * NX + xq * 4));
    }
}

// ---------------- fallbacks ----------------
__global__ void zero_vox_region_kernel(float* __restrict__ out) {
    int g = blockIdx.x * 256 + threadIdx.x;
    if (g >= B * C * NY * X4) return;
    int x4   = g % X4;
    int rest = g / X4;
    int y  = rest % NY;
    int bc = rest / NY;
    int c  = bc & (C - 1);
    int b  = bc >> 6;
    *(f32x4*)(out + (((size_t)b * CT + c) * NY + y) * NX + x4 * 4) = (f32x4)0.f;
}

__global__ void scatter_direct_kernel(const float* __restrict__ vox,
                                      const int* __restrict__ coords,
                                      float* __restrict__ out) {
    int p = blockIdx.x;
    int c = threadIdx.x;  // 0..63
    const int4 cd = ((const int4*)coords)[p];
    out[(((size_t)cd.x * CT + c) * NY + cd.z) * NX + cd.w] = vox[(size_t)p * C + c];
}

__global__ void map_only_kernel(const float* __restrict__ map,
                                float* __restrict__ out) {
    int g = blockIdx.x * 256 + threadIdx.x;
    if (g >= B * CMAP * NY * NX) return;
    int x    = g % NX;
    int rest = g / NX;
    int y  = rest % NY;
    int bc = rest / NY;
    int cm = bc & (CMAP - 1);
    int b  = bc >> 4;
    out[((size_t)b * CT + C + cm) * PL + (size_t)y * NX + x] =
        map[((size_t)(b * NX + x) * NY + y) * CMAP + cm];
}

extern "C" void kernel_launch(void* const* d_in, const int* in_sizes, int n_in,
                              void* d_out, int out_size, void* d_ws, size_t ws_size,
                              hipStream_t stream) {
    const float* vox    = (const float*)d_in[0];   // (P, 64) float32
    const int*   coords = (const int*)d_in[1];     // (P, 4) int32
    const float* map    = (const float*)d_in[3];   // (B, NX, NY, CMAP) float32
    float* out = (float*)d_out;                    // (B, 80, NY, NX) float32

    const size_t inv_bytes = (size_t)B * NY * NX * sizeof(int);  // 3.43 MB
    int* inv = (ws_size >= inv_bytes) ? (int*)d_ws : nullptr;

    if (inv) {
        (void)hipMemsetAsync(inv, 0xFF, inv_bytes, stream);      // all -1
        scatter_inv_kernel<<<(P + 255) / 256, 256, 0, stream>>>(coords, inv);
        vox_fill_kernel<<<dim3(1, NY / 2, B * CQ), 256, 0, stream>>>(vox, inv, out);
        map_xpose_kernel<<<dim3(NX / XT, NYT, B), 256, 0, stream>>>(map, out);
    } else {
        zero_vox_region_kernel<<<(B * C * NY * X4 + 255) / 256, 256, 0, stream>>>(out);
        scatter_direct_kernel<<<P, 64, 0, stream>>>(vox, coords, out);
        map_only_kernel<<<(B * CMAP * NY * NX + 255) / 256, 256, 0, stream>>>(map, out);
    }
}